// Round 7
// baseline (161.040 us; speedup 1.0000x reference)
//
#include <hip/hip_runtime.h>

#define IN_DIM 256
#define OUT_DIM 128
#define LEAKY 0.01f

typedef __attribute__((ext_vector_type(8))) short bf16x8;
typedef __attribute__((ext_vector_type(4))) float f32x4;

// RNE f32->bf16 pack (2 at a time). No builtin on gfx950 -> inline asm.
__device__ inline unsigned cvtpk_bf16(float lo, float hi) {
  unsigned r;
  asm volatile("v_cvt_pk_bf16_f32 %0, %1, %2" : "=v"(r) : "v"(lo), "v"(hi));
  return r;
}

__device__ inline float b2f(unsigned short u) {
  union { unsigned u; float f; } c;
  c.u = ((unsigned)u) << 16;
  return c.f;
}

// ---------------------------------------------------------------------------
// Kernel 0a: weight fp32 [128*256] -> bf16 bits.
// ---------------------------------------------------------------------------
__global__ __launch_bounds__(256) void wcvt(const float* __restrict__ w,
                                            unsigned* __restrict__ wbf) {
  int i = blockIdx.x * 256 + threadIdx.x;  // 16384 = 128*256/2
  float2 v = reinterpret_cast<const float2*>(w)[i];
  wbf[i] = cvtpk_bf16(v.x, v.y);
}

// ---------------------------------------------------------------------------
// Kernel 0b: row_starts[r] = lower_bound(erows, r); rs[nrows] = nedges.
// ---------------------------------------------------------------------------
__global__ __launch_bounds__(256) void row_bounds(const int* __restrict__ erows,
                                                  int* __restrict__ rs,
                                                  int nrows, int nedges) {
  int r = blockIdx.x * 256 + threadIdx.x;
  if (r > nrows) return;
  if (r == nrows) { rs[nrows] = nedges; return; }
  int lo = 0, hi = nedges;
  while (lo < hi) {
    int mid = (lo + hi) >> 1;
    if (erows[mid] < r) lo = mid + 1; else hi = mid;
  }
  rs[r] = lo;
}

// ---------------------------------------------------------------------------
// Kernel 1: support(bf16) = LeakyReLU(features @ W^T) via bf16 MFMA.
// R4 post-mortem: 128-row blocks gave a 782-block grid = 3 blocks/CU ->
// grid-limited occupancy (15%), regardless of LDS. Now 64-row blocks:
// grid = 1564 (6.1/CU), full K staged once in 32 KB LDS (5 blocks/CU by
// LDS), ONE barrier per block (stage -> sync -> compute). 4 waves arranged
// 2x2: (row-half ws, col-half wc); wave = 32 rows (2x16 stripes) x 64 cols,
// so each W fragment still feeds 2 MFMAs.
// Swizzle (0 conflicts measured in R4, same formula): 16B unit u of row r at
//   byte = r*512 + ((u&16)<<4) + (((u&15) ^ (r&15))<<4)
// W (bf16, 64 KB) direct from global: L2-hot.
// ---------------------------------------------------------------------------
__global__ __launch_bounds__(256, 4) void gemm_mfma(
    const float* __restrict__ feat, const unsigned short* __restrict__ wbf,
    unsigned short* __restrict__ support, int nrows) {
  __shared__ alignas(16) unsigned short fbuf[64 * 256];  // 32 KB, full K
  char* fb = reinterpret_cast<char*>(fbuf);

  const int t    = threadIdx.x;
  const int row0 = blockIdx.x * 64;

  // stage: 64 rows x 256 f32 -> bf16, coalesced-ish (32B/unit/thread)
#pragma unroll
  for (int it = 0; it < 8; ++it) {
    const int g = it * 256 + t;  // 0..2047
    const int r = g >> 5;        // 0..63
    const int u = g & 31;        // 16B bf16 unit = 8 source floats
    int gr = row0 + r;
    if (gr >= nrows) gr = nrows - 1;
    const float* src = &feat[gr * IN_DIM + u * 8];
    const float4 a = *reinterpret_cast<const float4*>(src);
    const float4 b = *reinterpret_cast<const float4*>(src + 4);
    uint4 pk;
    pk.x = cvtpk_bf16(a.x, a.y);
    pk.y = cvtpk_bf16(a.z, a.w);
    pk.z = cvtpk_bf16(b.x, b.y);
    pk.w = cvtpk_bf16(b.z, b.w);
    const int byte = r * 512 + ((u & 16) << 4) + (((u & 15) ^ (r & 15)) << 4);
    *reinterpret_cast<uint4*>(fb + byte) = pk;
  }
  __syncthreads();

  const int wid  = t >> 6;
  const int ws   = wid >> 1;  // row half (0/1)
  const int wc   = wid & 1;   // col half (0/1)
  const int lane = t & 63;
  const int lrow = lane & 15;
  const int hi   = lane >> 4;

  const unsigned short* wp = wbf + (wc * 64 + lrow) * IN_DIM + hi * 8;

  f32x4 acc[2][4];
#pragma unroll
  for (int s = 0; s < 2; ++s)
#pragma unroll
    for (int nt = 0; nt < 4; ++nt) acc[s][nt] = (f32x4){0.f, 0.f, 0.f, 0.f};

#pragma unroll
  for (int ks = 0; ks < 8; ++ks) {
    const int u = ks * 4 + hi;
    bf16x8 b[2];
#pragma unroll
    for (int s = 0; s < 2; ++s) {
      const int rl   = ws * 32 + s * 16 + lrow;
      const int byte =
          rl * 512 + ((u & 16) << 4) + (((u & 15) ^ (rl & 15)) << 4);
      b[s] = *reinterpret_cast<const bf16x8*>(fb + byte);
    }
#pragma unroll
    for (int nt = 0; nt < 4; ++nt) {
      const bf16x8 af =
          *reinterpret_cast<const bf16x8*>(wp + nt * 16 * IN_DIM + ks * 32);
      acc[0][nt] = __builtin_amdgcn_mfma_f32_16x16x32_bf16(af, b[0],
                                                           acc[0][nt], 0, 0, 0);
      acc[1][nt] = __builtin_amdgcn_mfma_f32_16x16x32_bf16(af, b[1],
                                                           acc[1][nt], 0, 0, 0);
    }
  }

#pragma unroll
  for (int s = 0; s < 2; ++s) {
    const int mrow = row0 + ws * 32 + s * 16 + lrow;
    if (mrow < nrows) {
      unsigned short* orow = support + mrow * OUT_DIM + wc * 64 + hi * 4;
#pragma unroll
      for (int nt = 0; nt < 4; ++nt) {
        f32x4 v = acc[s][nt];
        float a0 = v[0] > 0.f ? v[0] : LEAKY * v[0];
        float a1 = v[1] > 0.f ? v[1] : LEAKY * v[1];
        float a2 = v[2] > 0.f ? v[2] : LEAKY * v[2];
        float a3 = v[3] > 0.f ? v[3] : LEAKY * v[3];
        uint2 st;
        st.x = cvtpk_bf16(a0, a1);
        st.y = cvtpk_bf16(a2, a3);
        *reinterpret_cast<uint2*>(orow + nt * 16) = st;
      }
    }
  }
}

// ---------------------------------------------------------------------------
// Kernel 2: out[r] = sum over edges (r,c,v) of v * support_bf16[c]
// R6 post-mortem: __shfl broadcast = ds_bpermute chains -> regression; back
// to R4's predicated per-lane scheme, deepened. Per 16-edge batch: preload
// ALL (col,val) pairs (nontemporal - stream-once data, keep L2 for support),
// then 16 back-to-back 8B gathers into 4 rotating accumulators. One
// index-load latency per row (deg_avg=16), ~16 gathers in flight per group.
// ---------------------------------------------------------------------------
__global__ __launch_bounds__(256) void spmm_bf16(
    const int* __restrict__ rs, const int* __restrict__ ecols,
    const float* __restrict__ evals, const unsigned short* __restrict__ support,
    float* __restrict__ out, int nrows) {
  const int t    = threadIdx.x;
  const int lane = t & 31;
  const int row  = blockIdx.x * 8 + (t >> 5);
  if (row >= nrows) return;

  const int s = rs[row];
  const int e = rs[row + 1];

  f32x4 acc[4];
#pragma unroll
  for (int j = 0; j < 4; ++j) acc[j] = (f32x4){0.f, 0.f, 0.f, 0.f};

  for (int i = s; i < e; i += 16) {
    int   cj[16];
    float vj[16];
#pragma unroll
    for (int j = 0; j < 16; ++j) {
      const int  idx = i + j;
      const bool ok  = idx < e;
      const int  ci  = ok ? idx : e - 1;  // clamped, always valid
      cj[j] = __builtin_nontemporal_load(&ecols[ci]);
      const float v = __builtin_nontemporal_load(&evals[ci]);
      vj[j] = ok ? v : 0.f;
    }
#pragma unroll
    for (int j = 0; j < 16; ++j) {
      const ushort4 u = *reinterpret_cast<const ushort4*>(
          &support[cj[j] * OUT_DIM + lane * 4]);
      acc[j & 3].x += vj[j] * b2f(u.x);
      acc[j & 3].y += vj[j] * b2f(u.y);
      acc[j & 3].z += vj[j] * b2f(u.z);
      acc[j & 3].w += vj[j] * b2f(u.w);
    }
  }

  f32x4 r = acc[0];
  r += acc[1];
  r += acc[2];
  r += acc[3];
  __builtin_nontemporal_store(
      r, reinterpret_cast<f32x4*>(&out[row * OUT_DIM + lane * 4]));
}

// ---------------------------------------------------------------------------
extern "C" void kernel_launch(void* const* d_in, const int* in_sizes, int n_in,
                              void* d_out, int out_size, void* d_ws,
                              size_t ws_size, hipStream_t stream) {
  const float* features = (const float*)d_in[0];
  const float* weight   = (const float*)d_in[1];
  const int*   erows    = (const int*)d_in[2];
  const int*   ecols    = (const int*)d_in[3];
  const float* evals    = (const float*)d_in[4];
  float*       out      = (float*)d_out;

  const int nrows  = in_sizes[0] / IN_DIM;  // 100000
  const int nedges = in_sizes[2];           // 1600000

  // ws layout: support bf16 (25.6 MB) | wbf16 (64 KB) | row_starts (400 KB)
  unsigned short* support = (unsigned short*)d_ws;
  unsigned short* wbf =
      (unsigned short*)((char*)d_ws + (size_t)nrows * OUT_DIM * 2);
  int* rs = (int*)((char*)wbf + (size_t)OUT_DIM * IN_DIM * 2);

  wcvt<<<64, 256, 0, stream>>>(weight, (unsigned*)wbf);
  row_bounds<<<(nrows + 256) / 256, 256, 0, stream>>>(erows, rs, nrows, nedges);
  gemm_mfma<<<(nrows + 63) / 64, 256, 0, stream>>>(features, wbf, support,
                                                   nrows);
  spmm_bf16<<<(nrows + 7) / 8, 256, 0, stream>>>(rs, ecols, evals, support,
                                                 out, nrows);
}

// Round 8
// 102.079 us; speedup vs baseline: 1.5776x; 1.5776x over previous
//
#include <hip/hip_runtime.h>

#define IN_DIM 256
#define OUT_DIM 128
#define LEAKY 0.01f

typedef __attribute__((ext_vector_type(8))) short bf16x8;
typedef __attribute__((ext_vector_type(4))) float f32x4;

// RNE f32->bf16 pack (2 at a time). No builtin on gfx950 -> inline asm.
__device__ inline unsigned cvtpk_bf16(float lo, float hi) {
  unsigned r;
  asm volatile("v_cvt_pk_bf16_f32 %0, %1, %2" : "=v"(r) : "v"(lo), "v"(hi));
  return r;
}

__device__ inline float b2f(unsigned short u) {
  union { unsigned u; float f; } c;
  c.u = ((unsigned)u) << 16;
  return c.f;
}

// LDS swizzle for a [rows][256bf16] tile, measured 0 bank conflicts (R4):
// 16B unit u of row r lives at byte r*512 + ((u&16)<<4) + (((u&15)^(r&15))<<4)
__device__ inline int swz_byte(int r, int u) {
  return r * 512 + ((u & 16) << 4) + (((u & 15) ^ (r & 15)) << 4);
}

// ---------------------------------------------------------------------------
// Kernel 0a: weight fp32 [128*256] -> bf16 bits.
// ---------------------------------------------------------------------------
__global__ __launch_bounds__(256) void wcvt(const float* __restrict__ w,
                                            unsigned* __restrict__ wbf) {
  int i = blockIdx.x * 256 + threadIdx.x;  // 16384 = 128*256/2
  float2 v = reinterpret_cast<const float2*>(w)[i];
  wbf[i] = cvtpk_bf16(v.x, v.y);
}

// ---------------------------------------------------------------------------
// Kernel 0b: row_starts via adjacent-difference scan over sorted erows.
// rs[r] = lower_bound(erows, r). Thread i writes rs[r]=i for all r in
// (erows[i-1], erows[i]]; thread nedges-1 also fills the tail. One coalesced
// 6.4 MB read + 100K scattered writes (vs 100K x 21 dependent-load searches).
// ---------------------------------------------------------------------------
__global__ __launch_bounds__(256) void scan_bounds(const int* __restrict__ erows,
                                                   int* __restrict__ rs,
                                                   int nrows, int nedges) {
  int i = blockIdx.x * 256 + threadIdx.x;
  if (i >= nedges) return;
  const int cur  = erows[i];
  const int prev = (i == 0) ? -1 : erows[i - 1];
  for (int r = prev + 1; r <= cur; ++r) rs[r] = i;
  if (i == nedges - 1)
    for (int r = cur + 1; r <= nrows; ++r) rs[r] = nedges;
}

// ---------------------------------------------------------------------------
// Kernel 1: support(bf16) = LeakyReLU(features @ W^T) via bf16 MFMA.
// R2/R4/R7 post-mortem: all variants read W fragments from GLOBAL inside the
// MFMA loop -> 32 dependent ~200cy L2 loads per wave per tile = the shared
// bottleneck. Now: W (64 KB bf16) staged ONCE per block into swizzled LDS;
// features read direct from global (streamed once, no reuse -> no staging).
// 512 thr / 8 waves; wave = 16 rows x 128 cols; grid-stride over 128-row
// tiles. LDS 64 KB -> 2 blocks/CU = 16 waves/CU.
// ---------------------------------------------------------------------------
__global__ __launch_bounds__(512, 4) void gemm_mfma(
    const float* __restrict__ feat, const unsigned short* __restrict__ wbf,
    unsigned short* __restrict__ support, int nrows, int ntiles) {
  __shared__ alignas(16) unsigned short wlds[128 * 256];  // 64 KB, swizzled
  char* wb = reinterpret_cast<char*>(wlds);

  const int t = threadIdx.x;
  // stage W: 4096 16B units, 8 per thread, coalesced read, swizzled write
#pragma unroll
  for (int it = 0; it < 8; ++it) {
    const int g = it * 512 + t;  // unit index 0..4095
    const int r = g >> 5;        // W row 0..127
    const int u = g & 31;        // 16B unit within row
    const uint4 v = reinterpret_cast<const uint4*>(wbf)[g];
    *reinterpret_cast<uint4*>(wb + swz_byte(r, u)) = v;
  }
  __syncthreads();

  const int wid  = t >> 6;
  const int lane = t & 63;
  const int lrow = lane & 15;
  const int hi   = lane >> 4;

  for (int tile = blockIdx.x; tile < ntiles; tile += gridDim.x) {
    const int mrow = tile * 128 + wid * 16 + lrow;
    const int mr   = mrow < nrows ? mrow : nrows - 1;
    const float* fp = feat + mr * IN_DIM + hi * 8;

    f32x4 acc[8];
#pragma unroll
    for (int nt = 0; nt < 8; ++nt) acc[nt] = (f32x4){0.f, 0.f, 0.f, 0.f};

#pragma unroll
    for (int ks = 0; ks < 8; ++ks) {
      const float4 a = *reinterpret_cast<const float4*>(fp + ks * 32);
      const float4 b = *reinterpret_cast<const float4*>(fp + ks * 32 + 4);
      union { bf16x8 v; unsigned u[4]; } bf;
      bf.u[0] = cvtpk_bf16(a.x, a.y);
      bf.u[1] = cvtpk_bf16(a.z, a.w);
      bf.u[2] = cvtpk_bf16(b.x, b.y);
      bf.u[3] = cvtpk_bf16(b.z, b.w);
      const int u = ks * 4 + hi;
#pragma unroll
      for (int nt = 0; nt < 8; ++nt) {
        const bf16x8 af = *reinterpret_cast<const bf16x8*>(
            wb + swz_byte(nt * 16 + lrow, u));
        acc[nt] = __builtin_amdgcn_mfma_f32_16x16x32_bf16(af, bf.v, acc[nt],
                                                          0, 0, 0);
      }
    }

    if (mrow < nrows) {
      unsigned short* orow = support + mrow * OUT_DIM + hi * 4;
#pragma unroll
      for (int nt = 0; nt < 8; ++nt) {
        f32x4 v = acc[nt];
        float a0 = v[0] > 0.f ? v[0] : LEAKY * v[0];
        float a1 = v[1] > 0.f ? v[1] : LEAKY * v[1];
        float a2 = v[2] > 0.f ? v[2] : LEAKY * v[2];
        float a3 = v[3] > 0.f ? v[3] : LEAKY * v[3];
        uint2 st;
        st.x = cvtpk_bf16(a0, a1);
        st.y = cvtpk_bf16(a2, a3);
        *reinterpret_cast<uint2*>(orow + nt * 16) = st;
      }
    }
  }
}

// ---------------------------------------------------------------------------
// Kernel 2: out[r] = sum over edges (r,c,v) of v * support_bf16[c]
// EXACT R4 structure (best measured: 75 us) - predicated unroll-8, plain
// cached edge loads, 8 independent accumulators - plus nontemporal out store
// (out written once; keep L2 for the support table).
// ---------------------------------------------------------------------------
__global__ __launch_bounds__(256) void spmm_bf16(
    const int* __restrict__ rs, const int* __restrict__ ecols,
    const float* __restrict__ evals, const unsigned short* __restrict__ support,
    float* __restrict__ out, int nrows) {
  const int t    = threadIdx.x;
  const int lane = t & 31;
  const int row  = blockIdx.x * 8 + (t >> 5);
  if (row >= nrows) return;

  const int s = rs[row];
  const int e = rs[row + 1];

  f32x4 acc[8];
#pragma unroll
  for (int j = 0; j < 8; ++j) acc[j] = (f32x4){0.f, 0.f, 0.f, 0.f};

  for (int i = s; i < e; i += 8) {
    int   ii[8];
    float vv[8];
#pragma unroll
    for (int j = 0; j < 8; ++j) {
      const int  idx = i + j;
      const bool ok  = idx < e;
      ii[j] = ok ? idx : e - 1;
      vv[j] = ok ? evals[ii[j]] : 0.f;
    }
#pragma unroll
    for (int j = 0; j < 8; ++j) {
      const int c = ecols[ii[j]];
      const ushort4 u =
          *reinterpret_cast<const ushort4*>(&support[c * OUT_DIM + lane * 4]);
      acc[j].x += vv[j] * b2f(u.x);
      acc[j].y += vv[j] * b2f(u.y);
      acc[j].z += vv[j] * b2f(u.z);
      acc[j].w += vv[j] * b2f(u.w);
    }
  }

#pragma unroll
  for (int j = 1; j < 8; ++j) acc[0] += acc[j];
  __builtin_nontemporal_store(
      acc[0], reinterpret_cast<f32x4*>(&out[row * OUT_DIM + lane * 4]));
}

// ---------------------------------------------------------------------------
extern "C" void kernel_launch(void* const* d_in, const int* in_sizes, int n_in,
                              void* d_out, int out_size, void* d_ws,
                              size_t ws_size, hipStream_t stream) {
  const float* features = (const float*)d_in[0];
  const float* weight   = (const float*)d_in[1];
  const int*   erows    = (const int*)d_in[2];
  const int*   ecols    = (const int*)d_in[3];
  const float* evals    = (const float*)d_in[4];
  float*       out      = (float*)d_out;

  const int nrows  = in_sizes[0] / IN_DIM;  // 100000
  const int nedges = in_sizes[2];           // 1600000

  // ws layout: support bf16 (25.6 MB) | wbf16 (64 KB) | row_starts (400 KB)
  unsigned short* support = (unsigned short*)d_ws;
  unsigned short* wbf =
      (unsigned short*)((char*)d_ws + (size_t)nrows * OUT_DIM * 2);
  int* rs = (int*)((char*)wbf + (size_t)OUT_DIM * IN_DIM * 2);

  const int ntiles = (nrows + 127) / 128;

  wcvt<<<64, 256, 0, stream>>>(weight, (unsigned*)wbf);
  scan_bounds<<<(nedges + 255) / 256, 256, 0, stream>>>(erows, rs, nrows,
                                                        nedges);
  gemm_mfma<<<512, 512, 0, stream>>>(features, wbf, support, nrows, ntiles);
  spmm_bf16<<<(nrows + 7) / 8, 256, 0, stream>>>(rs, ecols, evals, support,
                                                 out, nrows);
}

// Round 9
// 98.549 us; speedup vs baseline: 1.6341x; 1.0358x over previous
//
#include <hip/hip_runtime.h>

#define IN_DIM 256
#define OUT_DIM 128
#define LEAKY 0.01f

typedef __attribute__((ext_vector_type(8))) short bf16x8;
typedef __attribute__((ext_vector_type(4))) float f32x4;

// RNE f32->bf16 pack (2 at a time). No builtin on gfx950 -> inline asm.
__device__ inline unsigned cvtpk_bf16(float lo, float hi) {
  unsigned r;
  asm volatile("v_cvt_pk_bf16_f32 %0, %1, %2" : "=v"(r) : "v"(lo), "v"(hi));
  return r;
}

__device__ inline float b2f(unsigned short u) {
  union { unsigned u; float f; } c;
  c.u = ((unsigned)u) << 16;
  return c.f;
}

// LDS swizzle for a [rows][256bf16] tile, measured 0 bank conflicts (R4/R8):
// 16B unit u of row r lives at byte r*512 + ((u&16)<<4) + (((u&15)^(r&15))<<4)
__device__ inline int swz_byte(int r, int u) {
  return r * 512 + ((u & 16) << 4) + (((u & 15) ^ (r & 15)) << 4);
}

// ---------------------------------------------------------------------------
// Kernel 0 (fused prep): blocks 0..63 convert W fp32->bf16 (16384 x float2);
// blocks 64+ do the adjacent-difference scan for row_starts.
// ---------------------------------------------------------------------------
__global__ __launch_bounds__(256) void prep(const float* __restrict__ w,
                                            unsigned* __restrict__ wbf,
                                            const int* __restrict__ erows,
                                            int* __restrict__ rs, int nrows,
                                            int nedges) {
  const int b = blockIdx.x;
  if (b < 64) {
    int i = b * 256 + threadIdx.x;
    float2 v = reinterpret_cast<const float2*>(w)[i];
    wbf[i] = cvtpk_bf16(v.x, v.y);
    return;
  }
  int i = (b - 64) * 256 + threadIdx.x;
  if (i >= nedges) return;
  const int cur  = erows[i];
  const int prev = (i == 0) ? -1 : erows[i - 1];
  for (int r = prev + 1; r <= cur; ++r) rs[r] = i;
  if (i == nedges - 1)
    for (int r = cur + 1; r <= nrows; ++r) rs[r] = nedges;
}

// ---------------------------------------------------------------------------
// Kernel 1: support(bf16) = LeakyReLU(features @ W^T) via bf16 MFMA.
// W (64 KB bf16) staged ONCE per block into swizzled LDS; features read
// direct from global (streamed once, no reuse). 512 thr / 8 waves; wave =
// 16 rows x 128 cols; grid-stride over 128-row tiles. ~= HBM floor (R8).
// ---------------------------------------------------------------------------
__global__ __launch_bounds__(512, 4) void gemm_mfma(
    const float* __restrict__ feat, const unsigned short* __restrict__ wbf,
    unsigned short* __restrict__ support, int nrows, int ntiles) {
  __shared__ alignas(16) unsigned short wlds[128 * 256];  // 64 KB, swizzled
  char* wb = reinterpret_cast<char*>(wlds);

  const int t = threadIdx.x;
#pragma unroll
  for (int it = 0; it < 8; ++it) {
    const int g = it * 512 + t;  // unit index 0..4095
    const int r = g >> 5;
    const int u = g & 31;
    const uint4 v = reinterpret_cast<const uint4*>(wbf)[g];
    *reinterpret_cast<uint4*>(wb + swz_byte(r, u)) = v;
  }
  __syncthreads();

  const int wid  = t >> 6;
  const int lane = t & 63;
  const int lrow = lane & 15;
  const int hi   = lane >> 4;

  for (int tile = blockIdx.x; tile < ntiles; tile += gridDim.x) {
    const int mrow = tile * 128 + wid * 16 + lrow;
    const int mr   = mrow < nrows ? mrow : nrows - 1;
    const float* fp = feat + mr * IN_DIM + hi * 8;

    f32x4 acc[8];
#pragma unroll
    for (int nt = 0; nt < 8; ++nt) acc[nt] = (f32x4){0.f, 0.f, 0.f, 0.f};

#pragma unroll
    for (int ks = 0; ks < 8; ++ks) {
      const float4 a = *reinterpret_cast<const float4*>(fp + ks * 32);
      const float4 b = *reinterpret_cast<const float4*>(fp + ks * 32 + 4);
      union { bf16x8 v; unsigned u[4]; } bf;
      bf.u[0] = cvtpk_bf16(a.x, a.y);
      bf.u[1] = cvtpk_bf16(a.z, a.w);
      bf.u[2] = cvtpk_bf16(b.x, b.y);
      bf.u[3] = cvtpk_bf16(b.z, b.w);
      const int u = ks * 4 + hi;
#pragma unroll
      for (int nt = 0; nt < 8; ++nt) {
        const bf16x8 af = *reinterpret_cast<const bf16x8*>(
            wb + swz_byte(nt * 16 + lrow, u));
        acc[nt] = __builtin_amdgcn_mfma_f32_16x16x32_bf16(af, bf.v, acc[nt],
                                                          0, 0, 0);
      }
    }

    if (mrow < nrows) {
      unsigned short* orow = support + mrow * OUT_DIM + hi * 4;
#pragma unroll
      for (int nt = 0; nt < 8; ++nt) {
        f32x4 v = acc[nt];
        float a0 = v[0] > 0.f ? v[0] : LEAKY * v[0];
        float a1 = v[1] > 0.f ? v[1] : LEAKY * v[1];
        float a2 = v[2] > 0.f ? v[2] : LEAKY * v[2];
        float a3 = v[3] > 0.f ? v[3] : LEAKY * v[3];
        uint2 st;
        st.x = cvtpk_bf16(a0, a1);
        st.y = cvtpk_bf16(a2, a3);
        *reinterpret_cast<uint2*>(orow + nt * 16) = st;
      }
    }
  }
}

// ---------------------------------------------------------------------------
// Kernel 2: out[r] = sum over edges (r,c,v) of v * support_bf16[c]
// R8 best structure, issue-optimized: UNPREDICATED full-8 batches (bulk)
// with an explicit software pipeline (next batch's 16 index loads issue
// before the current gather burst), predication only in the <=7-edge tail.
// 256 threads = 8 rows x 32 lanes; lane owns 4 cols (8B gathers); fp32 acc;
// nontemporal out store (write-once data, keep L2 for the support table).
// ---------------------------------------------------------------------------
__global__ __launch_bounds__(256) void spmm_bf16(
    const int* __restrict__ rs, const int* __restrict__ ecols,
    const float* __restrict__ evals, const unsigned short* __restrict__ support,
    float* __restrict__ out, int nrows) {
  const int t    = threadIdx.x;
  const int lane = t & 31;
  const int row  = blockIdx.x * 8 + (t >> 5);
  if (row >= nrows) return;

  const int s = rs[row];
  const int e = rs[row + 1];

  f32x4 acc[8];
#pragma unroll
  for (int j = 0; j < 8; ++j) acc[j] = (f32x4){0.f, 0.f, 0.f, 0.f};

  const int nfull = (e - s) >> 3;
  int i = s;

  if (nfull > 0) {
    int   c[8];
    float v[8];
#pragma unroll
    for (int j = 0; j < 8; ++j) {
      c[j] = ecols[s + j];
      v[j] = evals[s + j];
    }
    for (int b = 1; b < nfull; ++b) {
      int   c2[8];
      float v2[8];
      const int base = s + b * 8;
#pragma unroll
      for (int j = 0; j < 8; ++j) {  // issue NEXT batch's index loads first
        c2[j] = ecols[base + j];
        v2[j] = evals[base + j];
      }
#pragma unroll
      for (int j = 0; j < 8; ++j) {  // gather burst for CURRENT batch
        const ushort4 u = *reinterpret_cast<const ushort4*>(
            &support[c[j] * OUT_DIM + lane * 4]);
        acc[j].x += v[j] * b2f(u.x);
        acc[j].y += v[j] * b2f(u.y);
        acc[j].z += v[j] * b2f(u.z);
        acc[j].w += v[j] * b2f(u.w);
      }
#pragma unroll
      for (int j = 0; j < 8; ++j) {
        c[j] = c2[j];
        v[j] = v2[j];
      }
    }
#pragma unroll
    for (int j = 0; j < 8; ++j) {  // drain last full batch
      const ushort4 u = *reinterpret_cast<const ushort4*>(
          &support[c[j] * OUT_DIM + lane * 4]);
      acc[j].x += v[j] * b2f(u.x);
      acc[j].y += v[j] * b2f(u.y);
      acc[j].z += v[j] * b2f(u.z);
      acc[j].w += v[j] * b2f(u.w);
    }
    i = s + nfull * 8;
  }

  if (i < e) {  // predicated tail, 1..7 edges
    int   ii[8];
    float vv[8];
#pragma unroll
    for (int j = 0; j < 8; ++j) {
      const int  idx = i + j;
      const bool ok  = idx < e;
      ii[j] = ok ? idx : e - 1;
      vv[j] = ok ? evals[ii[j]] : 0.f;
    }
#pragma unroll
    for (int j = 0; j < 8; ++j) {
      const ushort4 u = *reinterpret_cast<const ushort4*>(
          &support[ecols[ii[j]] * OUT_DIM + lane * 4]);
      acc[j].x += vv[j] * b2f(u.x);
      acc[j].y += vv[j] * b2f(u.y);
      acc[j].z += vv[j] * b2f(u.z);
      acc[j].w += vv[j] * b2f(u.w);
    }
  }

#pragma unroll
  for (int j = 1; j < 8; ++j) acc[0] += acc[j];
  __builtin_nontemporal_store(
      acc[0], reinterpret_cast<f32x4*>(&out[row * OUT_DIM + lane * 4]));
}

// ---------------------------------------------------------------------------
extern "C" void kernel_launch(void* const* d_in, const int* in_sizes, int n_in,
                              void* d_out, int out_size, void* d_ws,
                              size_t ws_size, hipStream_t stream) {
  const float* features = (const float*)d_in[0];
  const float* weight   = (const float*)d_in[1];
  const int*   erows    = (const int*)d_in[2];
  const int*   ecols    = (const int*)d_in[3];
  const float* evals    = (const float*)d_in[4];
  float*       out      = (float*)d_out;

  const int nrows  = in_sizes[0] / IN_DIM;  // 100000
  const int nedges = in_sizes[2];           // 1600000

  // ws layout: support bf16 (25.6 MB) | wbf16 (64 KB) | row_starts (400 KB)
  unsigned short* support = (unsigned short*)d_ws;
  unsigned short* wbf =
      (unsigned short*)((char*)d_ws + (size_t)nrows * OUT_DIM * 2);
  int* rs = (int*)((char*)wbf + (size_t)OUT_DIM * IN_DIM * 2);

  const int ntiles = (nrows + 127) / 128;

  prep<<<64 + (nedges + 255) / 256, 256, 0, stream>>>(weight, (unsigned*)wbf,
                                                      erows, rs, nrows, nedges);
  gemm_mfma<<<512, 512, 0, stream>>>(features, wbf, support, nrows, ntiles);
  spmm_bf16<<<(nrows + 7) / 8, 256, 0, stream>>>(rs, ecols, evals, support,
                                                 out, nrows);
}

// Round 10
// 94.457 us; speedup vs baseline: 1.7049x; 1.0433x over previous
//
#include <hip/hip_runtime.h>

#define IN_DIM 256
#define OUT_DIM 128
#define LEAKY 0.01f
#define GEMM_BLOCKS 512

typedef __attribute__((ext_vector_type(8))) short bf16x8;
typedef __attribute__((ext_vector_type(4))) float f32x4;
typedef __attribute__((ext_vector_type(4))) unsigned u32x4;

// RNE f32->bf16 pack (2 at a time). No builtin on gfx950 -> inline asm.
__device__ inline unsigned cvtpk_bf16(float lo, float hi) {
  unsigned r;
  asm volatile("v_cvt_pk_bf16_f32 %0, %1, %2" : "=v"(r) : "v"(lo), "v"(hi));
  return r;
}

// unpack a u32 holding two bf16 (little-endian: low short = even col)
__device__ inline float blo(unsigned u) {
  union { unsigned x; float f; } c; c.x = u << 16; return c.f;
}
__device__ inline float bhi(unsigned u) {
  union { unsigned x; float f; } c; c.x = u & 0xFFFF0000u; return c.f;
}

// LDS swizzle for a [rows][256bf16] tile, measured 0 bank conflicts (R4/R8):
// 16B unit u of row r lives at byte r*512 + ((u&16)<<4) + (((u&15)^(r&15))<<4)
__device__ inline int swz_byte(int r, int u) {
  return r * 512 + ((u & 16) << 4) + (((u & 15) ^ (r & 15)) << 4);
}

// ---------------------------------------------------------------------------
// Kernel 1 (fused): blocks < GEMM_BLOCKS run the MFMA GEMM (converting W
// fp32->bf16 straight into swizzled LDS - no separate wcvt pass, no global
// wbf roundtrip, no inter-kernel dependency); blocks >= GEMM_BLOCKS run the
// adjacent-difference scan building row_starts for the spmm.
// GEMM: 512 thr / 8 waves; wave = 16 rows x 128 cols; features read direct
// from global (streamed once); grid-stride over 128-row tiles. ~HBM floor.
// ---------------------------------------------------------------------------
__global__ __launch_bounds__(512, 4) void gemm_scan(
    const float* __restrict__ feat, const float* __restrict__ w,
    const int* __restrict__ erows, unsigned short* __restrict__ support,
    int* __restrict__ rs, int nrows, int nedges, int ntiles) {
  if (blockIdx.x >= GEMM_BLOCKS) {
    // ---- scan part: rs[r] = lower_bound(erows, r), sentinel rs[nrows] ----
    const int i = (blockIdx.x - GEMM_BLOCKS) * 512 + threadIdx.x;
    if (i >= nedges) return;
    const int cur  = erows[i];
    const int prev = (i == 0) ? -1 : erows[i - 1];
    for (int r = prev + 1; r <= cur; ++r) rs[r] = i;
    if (i == nedges - 1)
      for (int r = cur + 1; r <= nrows; ++r) rs[r] = nedges;
    return;
  }

  // ---- GEMM part ----
  __shared__ alignas(16) unsigned short wlds[128 * 256];  // 64 KB, swizzled
  char* wb = reinterpret_cast<char*>(wlds);

  const int t = threadIdx.x;
  // stage W fp32 -> bf16 -> swizzled LDS (4096 16B units, 8 per thread)
#pragma unroll
  for (int it = 0; it < 8; ++it) {
    const int g = it * 512 + t;  // unit index 0..4095
    const int r = g >> 5;        // W row 0..127
    const int u = g & 31;        // 16B unit within row
    const float* src = w + r * IN_DIM + u * 8;
    const float4 a = *reinterpret_cast<const float4*>(src);
    const float4 b = *reinterpret_cast<const float4*>(src + 4);
    uint4 pk;
    pk.x = cvtpk_bf16(a.x, a.y);
    pk.y = cvtpk_bf16(a.z, a.w);
    pk.z = cvtpk_bf16(b.x, b.y);
    pk.w = cvtpk_bf16(b.z, b.w);
    *reinterpret_cast<uint4*>(wb + swz_byte(r, u)) = pk;
  }
  __syncthreads();

  const int wid  = t >> 6;
  const int lane = t & 63;
  const int lrow = lane & 15;
  const int hi   = lane >> 4;

  for (int tile = blockIdx.x; tile < ntiles; tile += GEMM_BLOCKS) {
    const int mrow = tile * 128 + wid * 16 + lrow;
    const int mr   = mrow < nrows ? mrow : nrows - 1;
    const float* fp = feat + mr * IN_DIM + hi * 8;

    f32x4 acc[8];
#pragma unroll
    for (int nt = 0; nt < 8; ++nt) acc[nt] = (f32x4){0.f, 0.f, 0.f, 0.f};

#pragma unroll
    for (int ks = 0; ks < 8; ++ks) {
      const float4 a = *reinterpret_cast<const float4*>(fp + ks * 32);
      const float4 b = *reinterpret_cast<const float4*>(fp + ks * 32 + 4);
      union { bf16x8 v; unsigned u[4]; } bf;
      bf.u[0] = cvtpk_bf16(a.x, a.y);
      bf.u[1] = cvtpk_bf16(a.z, a.w);
      bf.u[2] = cvtpk_bf16(b.x, b.y);
      bf.u[3] = cvtpk_bf16(b.z, b.w);
      const int u = ks * 4 + hi;
#pragma unroll
      for (int nt = 0; nt < 8; ++nt) {
        const bf16x8 af = *reinterpret_cast<const bf16x8*>(
            wb + swz_byte(nt * 16 + lrow, u));
        acc[nt] = __builtin_amdgcn_mfma_f32_16x16x32_bf16(af, bf.v, acc[nt],
                                                          0, 0, 0);
      }
    }

    if (mrow < nrows) {
      unsigned short* orow = support + mrow * OUT_DIM + hi * 4;
#pragma unroll
      for (int nt = 0; nt < 8; ++nt) {
        f32x4 v = acc[nt];
        float a0 = v[0] > 0.f ? v[0] : LEAKY * v[0];
        float a1 = v[1] > 0.f ? v[1] : LEAKY * v[1];
        float a2 = v[2] > 0.f ? v[2] : LEAKY * v[2];
        float a3 = v[3] > 0.f ? v[3] : LEAKY * v[3];
        uint2 st;
        st.x = cvtpk_bf16(a0, a1);
        st.y = cvtpk_bf16(a2, a3);
        *reinterpret_cast<uint2*>(orow + nt * 16) = st;
      }
    }
  }
}

// ---------------------------------------------------------------------------
// Kernel 2: out[r] = sum over edges (r,c,v) of v * support_bf16[c]
// R8's proven predicated unroll-8, with the gather WIDENED to the 16B/lane
// coalescing sweet spot: wave = 4 rows x 16 lanes, lane owns 8 cols and
// gathers u32x4 (16B) -> wave-gather instruction count halves (800K->400K),
// per-edge address math halves. 4 rotating acc slots (2x f32x4 per slot
// pair), fp32 accumulate, nontemporal out store.
// ---------------------------------------------------------------------------
__global__ __launch_bounds__(256) void spmm_bf16(
    const int* __restrict__ rs, const int* __restrict__ ecols,
    const float* __restrict__ evals, const unsigned short* __restrict__ support,
    float* __restrict__ out, int nrows) {
  const int t    = threadIdx.x;
  const int lane = t & 15;                   // 16 lanes per row
  const int row  = blockIdx.x * 16 + (t >> 4);
  if (row >= nrows) return;

  const int s = rs[row];
  const int e = rs[row + 1];

  f32x4 accA[4], accB[4];
#pragma unroll
  for (int j = 0; j < 4; ++j) {
    accA[j] = (f32x4){0.f, 0.f, 0.f, 0.f};
    accB[j] = (f32x4){0.f, 0.f, 0.f, 0.f};
  }

  const unsigned short* srow = support + lane * 8;

  for (int i = s; i < e; i += 8) {
    int   ii[8];
    float vv[8];
#pragma unroll
    for (int j = 0; j < 8; ++j) {
      const int  idx = i + j;
      const bool ok  = idx < e;
      ii[j] = ok ? idx : e - 1;
      vv[j] = ok ? evals[ii[j]] : 0.f;
    }
#pragma unroll
    for (int j = 0; j < 8; ++j) {
      const int c = ecols[ii[j]];
      const u32x4 u =
          *reinterpret_cast<const u32x4*>(srow + (size_t)c * OUT_DIM);
      const int   k = j & 3;
      const float v = vv[j];
      accA[k][0] += v * blo(u[0]);
      accA[k][1] += v * bhi(u[0]);
      accA[k][2] += v * blo(u[1]);
      accA[k][3] += v * bhi(u[1]);
      accB[k][0] += v * blo(u[2]);
      accB[k][1] += v * bhi(u[2]);
      accB[k][2] += v * blo(u[3]);
      accB[k][3] += v * bhi(u[3]);
    }
  }

#pragma unroll
  for (int j = 1; j < 4; ++j) {
    accA[0] += accA[j];
    accB[0] += accB[j];
  }
  float* orow = out + (size_t)row * OUT_DIM + lane * 8;
  __builtin_nontemporal_store(accA[0], reinterpret_cast<f32x4*>(orow));
  __builtin_nontemporal_store(accB[0], reinterpret_cast<f32x4*>(orow + 4));
}

// ---------------------------------------------------------------------------
extern "C" void kernel_launch(void* const* d_in, const int* in_sizes, int n_in,
                              void* d_out, int out_size, void* d_ws,
                              size_t ws_size, hipStream_t stream) {
  const float* features = (const float*)d_in[0];
  const float* weight   = (const float*)d_in[1];
  const int*   erows    = (const int*)d_in[2];
  const int*   ecols    = (const int*)d_in[3];
  const float* evals    = (const float*)d_in[4];
  float*       out      = (float*)d_out;

  const int nrows  = in_sizes[0] / IN_DIM;  // 100000
  const int nedges = in_sizes[2];           // 1600000

  // ws layout: support bf16 (25.6 MB) | row_starts (400 KB)
  unsigned short* support = (unsigned short*)d_ws;
  int* rs = (int*)((char*)d_ws + (size_t)nrows * OUT_DIM * 2);

  const int ntiles      = (nrows + 127) / 128;
  const int scan_blocks = (nedges + 511) / 512;

  gemm_scan<<<GEMM_BLOCKS + scan_blocks, 512, 0, stream>>>(
      features, weight, erows, support, rs, nrows, nedges, ntiles);
  spmm_bf16<<<(nrows + 15) / 16, 256, 0, stream>>>(rs, ecols, evals, support,
                                                   out, nrows);
}